// Round 10
// baseline (400.429 us; speedup 1.0000x reference)
//
#include <hip/hip_runtime.h>
#include <hip/hip_bf16.h>
#include <hip/hip_fp16.h>

#define B_    128
#define T_    200
#define C_    40
#define NCODE 2000
#define DAUX  16
#define E_    128
#define H_    256
#define G4    512          // 4*E
#define HCH   36           // padded LDS chunk stride (32 + 4) -> conflict-free

__device__ __forceinline__ float sigmoid_fast(float x) {
    return __fdividef(1.f, 1.f + __expf(-x));
}
__device__ __forceinline__ float tanh_fast(float x) {
    x = fminf(15.f, fmaxf(-15.f, x));
    float e = __expf(2.f * x);
    return __fdividef(e - 1.f, e + 1.f);
}

// ---------------------------------------------------------------------------
// Kernel 1: front-end. multi-hot (set semantics, drop code 0) @ W_lin + aux
// part + bias, ReLU. One workgroup per (b,t) cell, 128 threads.
// ---------------------------------------------------------------------------
__global__ __launch_bounds__(128) void fe_kernel(
    const int* __restrict__ code, const float* __restrict__ aux,
    const float* __restrict__ W_lin, const float* __restrict__ b_lin,
    const int* __restrict__ length, float* __restrict__ x)
{
    const int cell = blockIdx.x;          // b*T_ + t
    const int e = threadIdx.x;            // 0..127
    const int b = cell / T_;
    const int t = cell - b * T_;

    if (t >= length[b]) {                 // dead cell: zero-fill (uniform exit)
        x[(size_t)cell * E_ + e] = 0.f;
        return;
    }

    __shared__ int codes[C_];
    __shared__ int keep[C_];

    if (e < C_) {
        int cj = code[cell * C_ + e];
        codes[e] = cj;
        keep[e] = (cj != 0);
    }
    __syncthreads();
    // pair (i < jj, codes equal) -> jj is a duplicate of an earlier code
    for (int p = e; p < C_ * C_; p += 128) {
        int i  = p / C_;
        int jj = p - i * C_;
        if (i < jj && codes[i] == codes[jj]) keep[jj] = 0;
    }
    __syncthreads();

    float acc = b_lin[e];
    #pragma unroll 8
    for (int j = 0; j < C_; ++j) {
        int cj = codes[j];
        float w = (float)keep[j];
        int row = (cj > 0) ? (cj - 1) : 0;     // safe row even when skipped
        acc = fmaf(w, W_lin[row * E_ + e], acc);
    }
    const float* arow = aux + (size_t)cell * DAUX;
    #pragma unroll
    for (int d = 0; d < DAUX; ++d)
        acc = fmaf(arow[d], W_lin[(NCODE + d) * E_ + e], acc);

    x[(size_t)cell * E_ + e] = fmaxf(acc, 0.f);
}

// ---------------------------------------------------------------------------
// Kernel 2: z_pre = x @ W_x + b_lstm.   [25600,128] @ [128,512]
// 64x64 tiles, XOR-swizzled LDS, 4x4 micro-tile per thread.
// Tiles whose 64 rows are all dead exit early.
// ---------------------------------------------------------------------------
__global__ __launch_bounds__(256) void gemm_kernel(
    const float* __restrict__ x, const float* __restrict__ Wx,
    const float* __restrict__ bl, const int* __restrict__ length,
    float* __restrict__ z)
{
    const int m0 = blockIdx.x * 64;
    const int n0 = blockIdx.y * 64;

    {
        int b_first = m0 / T_;
        int b_last  = (m0 + 63) / T_;
        if (b_first == b_last && (m0 - b_first * T_) >= length[b_first])
            return;
    }

    __shared__ float4 As[64][32];   // [row][k4], col swizzled by (row&7)
    __shared__ float4 Bt[64][32];   // [col][k4], col swizzled by (col&7)

    const int tid = threadIdx.x;

    const float4* x4 = (const float4*)x;
    #pragma unroll
    for (int i = 0; i < 8; ++i) {
        int idx = tid + i * 256;              // 0..2047
        int r = idx >> 5, c = idx & 31;
        As[r][c ^ (r & 7)] = x4[(size_t)(m0 + r) * 32 + c];
    }
    #pragma unroll
    for (int i = 0; i < 32; ++i) {
        int idx = tid + i * 256;              // 0..8191
        int k = idx >> 6, n = idx & 63;       // consecutive n -> coalesced
        ((float*)&Bt[n][(k >> 2) ^ (n & 7)])[k & 3] = Wx[k * G4 + n0 + n];
    }
    __syncthreads();

    const int tn = tid & 15;
    const int tm = tid >> 4;
    float acc[4][4] = {};

    #pragma unroll
    for (int k4 = 0; k4 < 32; ++k4) {
        float4 a[4], bb[4];
        #pragma unroll
        for (int i = 0; i < 4; ++i) {
            int r = 4 * tm + i;
            a[i] = As[r][k4 ^ (r & 7)];
        }
        #pragma unroll
        for (int c = 0; c < 4; ++c)
            bb[c] = Bt[tn + 16 * c][k4 ^ (tn & 7)];
        #pragma unroll
        for (int i = 0; i < 4; ++i)
            #pragma unroll
            for (int c = 0; c < 4; ++c) {
                acc[i][c] = fmaf(a[i].x, bb[c].x, acc[i][c]);
                acc[i][c] = fmaf(a[i].y, bb[c].y, acc[i][c]);
                acc[i][c] = fmaf(a[i].z, bb[c].z, acc[i][c]);
                acc[i][c] = fmaf(a[i].w, bb[c].w, acc[i][c]);
            }
    }

    #pragma unroll
    for (int i = 0; i < 4; ++i) {
        int row = m0 + 4 * tm + i;
        #pragma unroll
        for (int c = 0; c < 4; ++c) {
            int col = n0 + tn + 16 * c;
            z[(size_t)row * G4 + col] = acc[i][c] + bl[col];
        }
    }
}

// ---------------------------------------------------------------------------
// Kernel 3: LSTM, AGPR-resident weights.
// R9 falsified the L2-BW model (fp16 halved bytes, dur unchanged). Corrected
// model: active-CU VALUBusy ≈ 21% x (256/128 CUs) x (200/100 len dilution)
// ≈ 85% -> the step loop is VALU-ISSUE-bound; the removable instructions are
// the per-step weight reload + address arithmetic the compiler re-emits
// because it won't hold weights in VGPRs across __syncthreads (R7/R8).
// Fix: store the 128 weight floats in AGPRs via inline-asm "a" constraints.
// Asm results CANNOT be rematerialized -> residency is structural, not a
// heuristic. Volatile reads keep the reads in-loop (1 VALU op each), so no
// 128-live-VGPR spill risk (R5 lesson). gfx950 unified RF: 84 VGPR + 128
// AGPR = 212 < 256 budget at 2 waves/EU.
// ---------------------------------------------------------------------------
__global__ __launch_bounds__(512, 2) void lstm_kernel(
    const float* __restrict__ z_pre, const float* __restrict__ Wh,
    const int* __restrict__ length, float* __restrict__ last_h)
{
    const int b  = blockIdx.x;
    const int tid = threadIdx.x;
    const int j  = tid >> 2;     // 0..127 gate column
    const int ks = tid & 3;      // k-quarter

    __shared__ float h_lds[2][4 * HCH];

    // Load weight slice and park it in AGPRs (128 regs/thread).
    float wa0[32], wa1[32], wa2[32], wa3[32];
    #pragma unroll
    for (int kk = 0; kk < 32; ++kk) {
        const float* row = Wh + (size_t)(32 * ks + kk) * G4 + j;
        float w0 = row[0], w1 = row[E_], w2 = row[2 * E_], w3 = row[3 * E_];
        asm volatile("v_accvgpr_write_b32 %0, %1" : "=a"(wa0[kk]) : "v"(w0));
        asm volatile("v_accvgpr_write_b32 %0, %1" : "=a"(wa1[kk]) : "v"(w1));
        asm volatile("v_accvgpr_write_b32 %0, %1" : "=a"(wa2[kk]) : "v"(w2));
        asm volatile("v_accvgpr_write_b32 %0, %1" : "=a"(wa3[kk]) : "v"(w3));
    }

    const int len = length[b];
    const float* zp = z_pre + (size_t)b * T_ * G4;

    if (tid < E_) h_lds[0][HCH * (tid >> 5) + (tid & 31)] = 0.f;
    float c_reg = 0.f;
    float z0 = zp[j], z1 = zp[E_ + j], z2 = zp[2 * E_ + j], z3 = zp[3 * E_ + j];
    __syncthreads();

    for (int s = 0; s < len; ++s) {
        const int cur = s & 1, nxt = cur ^ 1;

        // prefetch next step's z (hidden under this step's FMAs)
        const int tn = (s + 1 < len) ? s + 1 : s;
        const float* zn = zp + (size_t)tn * G4;
        float p0 = zn[j], p1 = zn[E_ + j], p2 = zn[2 * E_ + j], p3 = zn[3 * E_ + j];

        // h chunk for this k-quarter (padded, conflict-free; static reg idx)
        float hreg[32];
        #pragma unroll
        for (int q = 0; q < 8; ++q)
            *(float4*)&hreg[4 * q] =
                *(const float4*)&h_lds[cur][HCH * ks + 4 * q];

        // recurrent partials from ZERO (z added once, after the reduction);
        // weights come straight out of AGPRs: no loads, no address math.
        float a0 = 0.f, a1 = 0.f, a2 = 0.f, a3 = 0.f;
        #pragma unroll
        for (int kk = 0; kk < 32; ++kk) {
            float h = hreg[kk];
            float w0, w1, w2, w3;
            asm volatile("v_accvgpr_read_b32 %0, %1" : "=v"(w0) : "a"(wa0[kk]));
            asm volatile("v_accvgpr_read_b32 %0, %1" : "=v"(w1) : "a"(wa1[kk]));
            asm volatile("v_accvgpr_read_b32 %0, %1" : "=v"(w2) : "a"(wa2[kk]));
            asm volatile("v_accvgpr_read_b32 %0, %1" : "=v"(w3) : "a"(wa3[kk]));
            a0 = fmaf(h, w0, a0);
            a1 = fmaf(h, w1, a1);
            a2 = fmaf(h, w2, a2);
            a3 = fmaf(h, w3, a3);
        }
        // complete dot products across the 4 k-quarters (quad-local butterfly)
        a0 += __shfl_xor(a0, 1); a0 += __shfl_xor(a0, 2);
        a1 += __shfl_xor(a1, 1); a1 += __shfl_xor(a1, 2);
        a2 += __shfl_xor(a2, 1); a2 += __shfl_xor(a2, 2);
        a3 += __shfl_xor(a3, 1); a3 += __shfl_xor(a3, 2);
        a0 += z0; a1 += z1; a2 += z2; a3 += z3;

        // gates: i=a0, f=a1, g=a2, o=a3 (keras order)
        float ig = sigmoid_fast(a0);
        float fg = sigmoid_fast(a1);
        float gg = tanh_fast(a2);
        float og = sigmoid_fast(a3);
        c_reg = fg * c_reg + ig * gg;
        float h = og * tanh_fast(c_reg);

        if (ks == 0) {
            h_lds[nxt][HCH * (j >> 5) + (j & 31)] = h;
            if (s == len - 1) last_h[b * E_ + j] = h;
        }
        z0 = p0; z1 = p1; z2 = p2; z3 = p3;
        __syncthreads();
    }
}

// ---------------------------------------------------------------------------
// Kernel 4: MLP head + L2 normalize. One workgroup per batch row, 256 threads.
// ---------------------------------------------------------------------------
__global__ __launch_bounds__(256) void mlp_kernel(
    const float* __restrict__ last_h, const float* __restrict__ W0,
    const float* __restrict__ b0, const float* __restrict__ W1,
    const float* __restrict__ b1, float* __restrict__ out)
{
    const int b = blockIdx.x;
    const int j = threadIdx.x;    // 0..255

    __shared__ float lrow[E_];
    __shared__ float hid[H_];
    __shared__ float red[H_];

    if (j < E_) lrow[j] = last_h[b * E_ + j];
    __syncthreads();

    float a = b0[j];
    #pragma unroll 8
    for (int k = 0; k < E_; ++k)
        a = fmaf(lrow[k], W0[k * H_ + j], a);
    hid[j] = fmaxf(a, 0.f);
    __syncthreads();

    float f = b1[j];
    #pragma unroll 8
    for (int k = 0; k < H_; ++k)
        f = fmaf(hid[k], W1[k * H_ + j], f);

    red[j] = f * f;
    __syncthreads();
    #pragma unroll
    for (int s = 128; s > 0; s >>= 1) {
        if (j < s) red[j] += red[j + s];
        __syncthreads();
    }
    out[(size_t)b * H_ + j] = f / sqrtf(red[0]);
}

// ---------------------------------------------------------------------------
extern "C" void kernel_launch(void* const* d_in, const int* in_sizes, int n_in,
                              void* d_out, int out_size, void* d_ws, size_t ws_size,
                              hipStream_t stream)
{
    const int*   code  = (const int*)  d_in[0];
    const float* aux   = (const float*)d_in[1];
    const int*   length= (const int*)  d_in[2];
    // d_in[3] = is_training (ignored; inference path)
    const float* W_lin = (const float*)d_in[4];
    const float* b_lin = (const float*)d_in[5];
    const float* W_x   = (const float*)d_in[6];
    const float* W_h   = (const float*)d_in[7];
    const float* b_lstm= (const float*)d_in[8];
    const float* W0    = (const float*)d_in[9];
    const float* b0    = (const float*)d_in[10];
    const float* W1    = (const float*)d_in[11];
    const float* b1    = (const float*)d_in[12];
    float* out = (float*)d_out;

    // workspace layout
    char* ws = (char*)d_ws;
    float* x      = (float*)ws;                                   // 25600*128 f32
    float* z_pre  = (float*)(ws + (size_t)B_ * T_ * E_ * 4);      // 25600*512 f32
    float* last_h = (float*)(ws + (size_t)B_ * T_ * E_ * 4
                                + (size_t)B_ * T_ * G4 * 4);      // 128*128 f32

    fe_kernel<<<B_ * T_, 128, 0, stream>>>(code, aux, W_lin, b_lin, length, x);
    gemm_kernel<<<dim3((B_ * T_) / 64, G4 / 64), 256, 0, stream>>>(x, W_x, b_lstm, length, z_pre);
    lstm_kernel<<<B_, 512, 0, stream>>>(z_pre, W_h, length, last_h);
    mlp_kernel<<<B_, H_, 0, stream>>>(last_h, W0, b0, W1, b1, out);
}

// Round 11
// 299.833 us; speedup vs baseline: 1.3355x; 1.3355x over previous
//
#include <hip/hip_runtime.h>
#include <hip/hip_bf16.h>
#include <hip/hip_fp16.h>

#define B_    128
#define T_    200
#define C_    40
#define NCODE 2000
#define DAUX  16
#define E_    128
#define H_    256
#define G4    512          // 4*E

typedef _Float16 half8 __attribute__((ext_vector_type(8)));
typedef float    floatx4 __attribute__((ext_vector_type(4)));

__device__ __forceinline__ float sigmoid_fast(float x) {
    return __fdividef(1.f, 1.f + __expf(-x));
}
__device__ __forceinline__ float tanh_fast(float x) {
    x = fminf(15.f, fmaxf(-15.f, x));
    float e = __expf(2.f * x);
    return __fdividef(e - 1.f, e + 1.f);
}

// ---------------------------------------------------------------------------
// Kernel 1: front-end (unchanged from R9).
// ---------------------------------------------------------------------------
__global__ __launch_bounds__(128) void fe_kernel(
    const int* __restrict__ code, const float* __restrict__ aux,
    const float* __restrict__ W_lin, const float* __restrict__ b_lin,
    const int* __restrict__ length, float* __restrict__ x)
{
    const int cell = blockIdx.x;          // b*T_ + t
    const int e = threadIdx.x;            // 0..127
    const int b = cell / T_;
    const int t = cell - b * T_;

    if (t >= length[b]) {                 // dead cell: zero-fill (uniform exit)
        x[(size_t)cell * E_ + e] = 0.f;
        return;
    }

    __shared__ int codes[C_];
    __shared__ int keep[C_];

    if (e < C_) {
        int cj = code[cell * C_ + e];
        codes[e] = cj;
        keep[e] = (cj != 0);
    }
    __syncthreads();
    for (int p = e; p < C_ * C_; p += 128) {
        int i  = p / C_;
        int jj = p - i * C_;
        if (i < jj && codes[i] == codes[jj]) keep[jj] = 0;
    }
    __syncthreads();

    float acc = b_lin[e];
    #pragma unroll 8
    for (int j = 0; j < C_; ++j) {
        int cj = codes[j];
        float w = (float)keep[j];
        int row = (cj > 0) ? (cj - 1) : 0;
        acc = fmaf(w, W_lin[row * E_ + e], acc);
    }
    const float* arow = aux + (size_t)cell * DAUX;
    #pragma unroll
    for (int d = 0; d < DAUX; ++d)
        acc = fmaf(arow[d], W_lin[(NCODE + d) * E_ + e], acc);

    x[(size_t)cell * E_ + e] = fmaxf(acc, 0.f);
}

// ---------------------------------------------------------------------------
// Kernel 2: z_pre = x @ W_x + b_lstm (unchanged).
// ---------------------------------------------------------------------------
__global__ __launch_bounds__(256) void gemm_kernel(
    const float* __restrict__ x, const float* __restrict__ Wx,
    const float* __restrict__ bl, const int* __restrict__ length,
    float* __restrict__ z)
{
    const int m0 = blockIdx.x * 64;
    const int n0 = blockIdx.y * 64;

    {
        int b_first = m0 / T_;
        int b_last  = (m0 + 63) / T_;
        if (b_first == b_last && (m0 - b_first * T_) >= length[b_first])
            return;
    }

    __shared__ float4 As[64][32];
    __shared__ float4 Bt[64][32];

    const int tid = threadIdx.x;

    const float4* x4 = (const float4*)x;
    #pragma unroll
    for (int i = 0; i < 8; ++i) {
        int idx = tid + i * 256;
        int r = idx >> 5, c = idx & 31;
        As[r][c ^ (r & 7)] = x4[(size_t)(m0 + r) * 32 + c];
    }
    #pragma unroll
    for (int i = 0; i < 32; ++i) {
        int idx = tid + i * 256;
        int k = idx >> 6, n = idx & 63;
        ((float*)&Bt[n][(k >> 2) ^ (n & 7)])[k & 3] = Wx[k * G4 + n0 + n];
    }
    __syncthreads();

    const int tn = tid & 15;
    const int tm = tid >> 4;
    float acc[4][4] = {};

    #pragma unroll
    for (int k4 = 0; k4 < 32; ++k4) {
        float4 a[4], bb[4];
        #pragma unroll
        for (int i = 0; i < 4; ++i) {
            int r = 4 * tm + i;
            a[i] = As[r][k4 ^ (r & 7)];
        }
        #pragma unroll
        for (int c = 0; c < 4; ++c)
            bb[c] = Bt[tn + 16 * c][k4 ^ (tn & 7)];
        #pragma unroll
        for (int i = 0; i < 4; ++i)
            #pragma unroll
            for (int c = 0; c < 4; ++c) {
                acc[i][c] = fmaf(a[i].x, bb[c].x, acc[i][c]);
                acc[i][c] = fmaf(a[i].y, bb[c].y, acc[i][c]);
                acc[i][c] = fmaf(a[i].z, bb[c].z, acc[i][c]);
                acc[i][c] = fmaf(a[i].w, bb[c].w, acc[i][c]);
            }
    }

    #pragma unroll
    for (int i = 0; i < 4; ++i) {
        int row = m0 + 4 * tm + i;
        #pragma unroll
        for (int c = 0; c < 4; ++c) {
            int col = n0 + tn + 16 * c;
            z[(size_t)row * G4 + col] = acc[i][c] + bl[col];
        }
    }
}

// ---------------------------------------------------------------------------
// Kernel 3: LSTM via MFMA (R10 confirmed the step loop is VALU-ISSUE-bound:
// per-step time ∝ instructions/SIMD; all byte-reduction attempts were null).
// One block per batch row, 8 waves. Wave w owns h-cols [16w,16w+16):
//   - 4 gate-tiles (n = g*128+16w) x 4 k-slices = 16 v_mfma_f32_16x16x32_f16
//     per step; M=1 of 16 rows used (matrix pipe is idle anyway).
//   - B-frags (weights, fp16) are loop-invariant regs. Remat hazard is moot:
//     even if RA parks them in AGPRs, MFMA reads AGPRs natively (gfx950).
//   - h: fp16[128] in LDS, double-buffered; A-frags via broadcast
//     ds_read_b128 (16-lane same-address groups -> conflict-free).
//   - z injected through the MFMA C operand: C row0 = z (C/D layout
//     col=lane&15, row=(lane>>4)*4+reg, HW-verified m89); garbage rows are
//     never read.
//   - acts: ~30 VALU, meaningful only in lanes 0-15 (reg 0 = row 0).
// Per-step/thread ~60 instr vs ~530 before -> predict 178 -> 30-50 us.
// ---------------------------------------------------------------------------
__global__ __launch_bounds__(512, 2) void lstm_kernel(
    const float* __restrict__ z_pre, const float* __restrict__ Wh,
    const int* __restrict__ length, float* __restrict__ last_h)
{
    const int b   = blockIdx.x;
    const int tid = threadIdx.x;
    const int w   = tid >> 6;       // wave 0..7
    const int l   = tid & 63;       // lane
    const int col = l & 15;         // n within tile / output col within wave
    const int kg  = l >> 4;         // k-group 0..3

    __shared__ __align__(16) _Float16 hbuf[2][E_];

    // ---- loop-invariant B fragments: bf[gate][kslice], 8 fp16 each ----
    // B layout: col = lane&15, k = kslice*32 + (lane>>4)*8 + e
    half8 bf[4][4];
    #pragma unroll
    for (int g = 0; g < 4; ++g) {
        const int ncol = g * E_ + w * 16 + col;
        #pragma unroll
        for (int s4 = 0; s4 < 4; ++s4) {
            const int k0 = s4 * 32 + kg * 8;
            half8 hb;
            #pragma unroll
            for (int e = 0; e < 8; ++e)
                hb[e] = (_Float16)Wh[(size_t)(k0 + e) * G4 + ncol];
            bf[g][s4] = hb;
        }
    }

    const int len = length[b];
    const float* zp = z_pre + (size_t)b * T_ * G4;

    if (tid < E_) hbuf[0][tid] = (_Float16)0.f;
    float c_st = 0.f;                         // valid in lanes 0-15
    // z for t=0 (z_pre already contains b_lstm)
    float zt0 = zp[0 * E_ + w * 16 + col];
    float zt1 = zp[1 * E_ + w * 16 + col];
    float zt2 = zp[2 * E_ + w * 16 + col];
    float zt3 = zp[3 * E_ + w * 16 + col];
    __syncthreads();

    for (int s = 0; s < len; ++s) {
        const int cur = s & 1, nxt = cur ^ 1;

        // prefetch next step's z
        const int tn = (s + 1 < len) ? s + 1 : s;
        const float* zn = zp + (size_t)tn * G4 + w * 16 + col;
        float p0 = zn[0], p1 = zn[E_], p2 = zn[2 * E_], p3 = zn[3 * E_];

        // A fragments: broadcast reads of h (row 0 of A; rows 1-15 get
        // harmless copies -> they only feed garbage output rows)
        half8 af0 = *(const half8*)&hbuf[cur][0 * 32 + kg * 8];
        half8 af1 = *(const half8*)&hbuf[cur][1 * 32 + kg * 8];
        half8 af2 = *(const half8*)&hbuf[cur][2 * 32 + kg * 8];
        half8 af3 = *(const half8*)&hbuf[cur][3 * 32 + kg * 8];

        // per-gate: acc = h(1x128) @ Wh(128x16) + z  on the matrix pipe
        floatx4 a0 = {zt0, 0.f, 0.f, 0.f};
        floatx4 a1 = {zt1, 0.f, 0.f, 0.f};
        floatx4 a2 = {zt2, 0.f, 0.f, 0.f};
        floatx4 a3 = {zt3, 0.f, 0.f, 0.f};
        a0 = __builtin_amdgcn_mfma_f32_16x16x32_f16(af0, bf[0][0], a0, 0, 0, 0);
        a0 = __builtin_amdgcn_mfma_f32_16x16x32_f16(af1, bf[0][1], a0, 0, 0, 0);
        a0 = __builtin_amdgcn_mfma_f32_16x16x32_f16(af2, bf[0][2], a0, 0, 0, 0);
        a0 = __builtin_amdgcn_mfma_f32_16x16x32_f16(af3, bf[0][3], a0, 0, 0, 0);
        a1 = __builtin_amdgcn_mfma_f32_16x16x32_f16(af0, bf[1][0], a1, 0, 0, 0);
        a1 = __builtin_amdgcn_mfma_f32_16x16x32_f16(af1, bf[1][1], a1, 0, 0, 0);
        a1 = __builtin_amdgcn_mfma_f32_16x16x32_f16(af2, bf[1][2], a1, 0, 0, 0);
        a1 = __builtin_amdgcn_mfma_f32_16x16x32_f16(af3, bf[1][3], a1, 0, 0, 0);
        a2 = __builtin_amdgcn_mfma_f32_16x16x32_f16(af0, bf[2][0], a2, 0, 0, 0);
        a2 = __builtin_amdgcn_mfma_f32_16x16x32_f16(af1, bf[2][1], a2, 0, 0, 0);
        a2 = __builtin_amdgcn_mfma_f32_16x16x32_f16(af2, bf[2][2], a2, 0, 0, 0);
        a2 = __builtin_amdgcn_mfma_f32_16x16x32_f16(af3, bf[2][3], a2, 0, 0, 0);
        a3 = __builtin_amdgcn_mfma_f32_16x16x32_f16(af0, bf[3][0], a3, 0, 0, 0);
        a3 = __builtin_amdgcn_mfma_f32_16x16x32_f16(af1, bf[3][1], a3, 0, 0, 0);
        a3 = __builtin_amdgcn_mfma_f32_16x16x32_f16(af2, bf[3][2], a3, 0, 0, 0);
        a3 = __builtin_amdgcn_mfma_f32_16x16x32_f16(af3, bf[3][3], a3, 0, 0, 0);

        // activations: element 0 of each acc = (row 0, this lane's col).
        // Only lanes 0-15 (kg==0) are meaningful; others compute harmless
        // finite garbage and never write.
        float ig = sigmoid_fast(a0[0]);
        float fg = sigmoid_fast(a1[0]);
        float gg = tanh_fast(a2[0]);
        float og = sigmoid_fast(a3[0]);
        c_st = fg * c_st + ig * gg;
        float h = og * tanh_fast(c_st);

        if (kg == 0) {
            hbuf[nxt][w * 16 + col] = (_Float16)h;
            if (s == len - 1) last_h[b * E_ + w * 16 + col] = h;
        }
        zt0 = p0; zt1 = p1; zt2 = p2; zt3 = p3;
        __syncthreads();    // h[nxt] complete before next step reads it
    }
}

// ---------------------------------------------------------------------------
// Kernel 4: MLP head + L2 normalize (unchanged).
// ---------------------------------------------------------------------------
__global__ __launch_bounds__(256) void mlp_kernel(
    const float* __restrict__ last_h, const float* __restrict__ W0,
    const float* __restrict__ b0, const float* __restrict__ W1,
    const float* __restrict__ b1, float* __restrict__ out)
{
    const int b = blockIdx.x;
    const int j = threadIdx.x;    // 0..255

    __shared__ float lrow[E_];
    __shared__ float hid[H_];
    __shared__ float red[H_];

    if (j < E_) lrow[j] = last_h[b * E_ + j];
    __syncthreads();

    float a = b0[j];
    #pragma unroll 8
    for (int k = 0; k < E_; ++k)
        a = fmaf(lrow[k], W0[k * H_ + j], a);
    hid[j] = fmaxf(a, 0.f);
    __syncthreads();

    float f = b1[j];
    #pragma unroll 8
    for (int k = 0; k < H_; ++k)
        f = fmaf(hid[k], W1[k * H_ + j], f);

    red[j] = f * f;
    __syncthreads();
    #pragma unroll
    for (int s = 128; s > 0; s >>= 1) {
        if (j < s) red[j] += red[j + s];
        __syncthreads();
    }
    out[(size_t)b * H_ + j] = f / sqrtf(red[0]);
}

// ---------------------------------------------------------------------------
extern "C" void kernel_launch(void* const* d_in, const int* in_sizes, int n_in,
                              void* d_out, int out_size, void* d_ws, size_t ws_size,
                              hipStream_t stream)
{
    const int*   code  = (const int*)  d_in[0];
    const float* aux   = (const float*)d_in[1];
    const int*   length= (const int*)  d_in[2];
    // d_in[3] = is_training (ignored; inference path)
    const float* W_lin = (const float*)d_in[4];
    const float* b_lin = (const float*)d_in[5];
    const float* W_x   = (const float*)d_in[6];
    const float* W_h   = (const float*)d_in[7];
    const float* b_lstm= (const float*)d_in[8];
    const float* W0    = (const float*)d_in[9];
    const float* b0    = (const float*)d_in[10];
    const float* W1    = (const float*)d_in[11];
    const float* b1    = (const float*)d_in[12];
    float* out = (float*)d_out;

    // workspace layout
    char* ws = (char*)d_ws;
    float* x      = (float*)ws;                                   // 25600*128 f32
    float* z_pre  = (float*)(ws + (size_t)B_ * T_ * E_ * 4);      // 25600*512 f32
    float* last_h = (float*)(ws + (size_t)B_ * T_ * E_ * 4
                                + (size_t)B_ * T_ * G4 * 4);      // 128*128 f32

    fe_kernel<<<B_ * T_, 128, 0, stream>>>(code, aux, W_lin, b_lin, length, x);
    gemm_kernel<<<dim3((B_ * T_) / 64, G4 / 64), 256, 0, stream>>>(x, W_x, b_lstm, length, z_pre);
    lstm_kernel<<<B_, 512, 0, stream>>>(z_pre, W_h, length, last_h);
    mlp_kernel<<<B_, H_, 0, stream>>>(last_h, W0, b0, W1, b1, out);
}

// Round 12
// 293.396 us; speedup vs baseline: 1.3648x; 1.0219x over previous
//
#include <hip/hip_runtime.h>
#include <hip/hip_bf16.h>
#include <hip/hip_fp16.h>

#define B_    128
#define T_    200
#define C_    40
#define NCODE 2000
#define DAUX  16
#define E_    128
#define H_    256
#define G4    512          // 4*E

typedef _Float16 half8 __attribute__((ext_vector_type(8)));
typedef float    floatx4 __attribute__((ext_vector_type(4)));

__device__ __forceinline__ float sigmoid_fast(float x) {
    return __fdividef(1.f, 1.f + __expf(-x));
}
__device__ __forceinline__ float tanh_fast(float x) {
    x = fminf(15.f, fmaxf(-15.f, x));
    float e = __expf(2.f * x);
    return __fdividef(e - 1.f, e + 1.f);
}

// ---------------------------------------------------------------------------
// Kernel 1: front-end (unchanged).
// ---------------------------------------------------------------------------
__global__ __launch_bounds__(128) void fe_kernel(
    const int* __restrict__ code, const float* __restrict__ aux,
    const float* __restrict__ W_lin, const float* __restrict__ b_lin,
    const int* __restrict__ length, float* __restrict__ x)
{
    const int cell = blockIdx.x;          // b*T_ + t
    const int e = threadIdx.x;            // 0..127
    const int b = cell / T_;
    const int t = cell - b * T_;

    if (t >= length[b]) {                 // dead cell: zero-fill (uniform exit)
        x[(size_t)cell * E_ + e] = 0.f;
        return;
    }

    __shared__ int codes[C_];
    __shared__ int keep[C_];

    if (e < C_) {
        int cj = code[cell * C_ + e];
        codes[e] = cj;
        keep[e] = (cj != 0);
    }
    __syncthreads();
    for (int p = e; p < C_ * C_; p += 128) {
        int i  = p / C_;
        int jj = p - i * C_;
        if (i < jj && codes[i] == codes[jj]) keep[jj] = 0;
    }
    __syncthreads();

    float acc = b_lin[e];
    #pragma unroll 8
    for (int j = 0; j < C_; ++j) {
        int cj = codes[j];
        float w = (float)keep[j];
        int row = (cj > 0) ? (cj - 1) : 0;
        acc = fmaf(w, W_lin[row * E_ + e], acc);
    }
    const float* arow = aux + (size_t)cell * DAUX;
    #pragma unroll
    for (int d = 0; d < DAUX; ++d)
        acc = fmaf(arow[d], W_lin[(NCODE + d) * E_ + e], acc);

    x[(size_t)cell * E_ + e] = fmaxf(acc, 0.f);
}

// ---------------------------------------------------------------------------
// Kernel 2: z_pre = x @ W_x + b_lstm (unchanged).
// ---------------------------------------------------------------------------
__global__ __launch_bounds__(256) void gemm_kernel(
    const float* __restrict__ x, const float* __restrict__ Wx,
    const float* __restrict__ bl, const int* __restrict__ length,
    float* __restrict__ z)
{
    const int m0 = blockIdx.x * 64;
    const int n0 = blockIdx.y * 64;

    {
        int b_first = m0 / T_;
        int b_last  = (m0 + 63) / T_;
        if (b_first == b_last && (m0 - b_first * T_) >= length[b_first])
            return;
    }

    __shared__ float4 As[64][32];
    __shared__ float4 Bt[64][32];

    const int tid = threadIdx.x;

    const float4* x4 = (const float4*)x;
    #pragma unroll
    for (int i = 0; i < 8; ++i) {
        int idx = tid + i * 256;
        int r = idx >> 5, c = idx & 31;
        As[r][c ^ (r & 7)] = x4[(size_t)(m0 + r) * 32 + c];
    }
    #pragma unroll
    for (int i = 0; i < 32; ++i) {
        int idx = tid + i * 256;
        int k = idx >> 6, n = idx & 63;
        ((float*)&Bt[n][(k >> 2) ^ (n & 7)])[k & 3] = Wx[k * G4 + n0 + n];
    }
    __syncthreads();

    const int tn = tid & 15;
    const int tm = tid >> 4;
    float acc[4][4] = {};

    #pragma unroll
    for (int k4 = 0; k4 < 32; ++k4) {
        float4 a[4], bb[4];
        #pragma unroll
        for (int i = 0; i < 4; ++i) {
            int r = 4 * tm + i;
            a[i] = As[r][k4 ^ (r & 7)];
        }
        #pragma unroll
        for (int c = 0; c < 4; ++c)
            bb[c] = Bt[tn + 16 * c][k4 ^ (tn & 7)];
        #pragma unroll
        for (int i = 0; i < 4; ++i)
            #pragma unroll
            for (int c = 0; c < 4; ++c) {
                acc[i][c] = fmaf(a[i].x, bb[c].x, acc[i][c]);
                acc[i][c] = fmaf(a[i].y, bb[c].y, acc[i][c]);
                acc[i][c] = fmaf(a[i].z, bb[c].z, acc[i][c]);
                acc[i][c] = fmaf(a[i].w, bb[c].w, acc[i][c]);
            }
    }

    #pragma unroll
    for (int i = 0; i < 4; ++i) {
        int row = m0 + 4 * tm + i;
        #pragma unroll
        for (int c = 0; c < 4; ++c) {
            int col = n0 + tn + 16 * c;
            z[(size_t)row * G4 + col] = acc[i][c] + bl[col];
        }
    }
}

// ---------------------------------------------------------------------------
// Kernel 3: LSTM via MFMA with DEPTH-2 z prefetch.
// R11 measured 1600 cy/step vs ~500 cy chain model: the z loads were issued
// and consumed within the SAME step (~350 cy in flight) while z_pre is
// half-HBM (~900 cy) -> per-step stall. Fix: unroll the step loop by 2 with
// two NAMED pending register sets (zA/zB, static indices per R5 lesson):
// step t consumes the set loaded at t-2 (~2 steps ≈ 1100 cy in flight) and
// re-issues it for t+2. h double-buffer becomes statically indexed (even
// half: read hbuf[0] write hbuf[1]; odd half reversed).
// Everything else identical to R11 (verified: absmax 9.8e-4, MfmaUtil>0).
// ---------------------------------------------------------------------------
__global__ __launch_bounds__(512, 2) void lstm_kernel(
    const float* __restrict__ z_pre, const float* __restrict__ Wh,
    const int* __restrict__ length, float* __restrict__ last_h)
{
    const int b   = blockIdx.x;
    const int tid = threadIdx.x;
    const int w   = tid >> 6;       // wave 0..7
    const int l   = tid & 63;       // lane
    const int col = l & 15;         // n within tile
    const int kg  = l >> 4;         // k-group 0..3

    __shared__ __align__(16) _Float16 hbuf[2][E_];

    // ---- loop-invariant B fragments: bf[gate][kslice], 8 fp16 each ----
    half8 bf[4][4];
    #pragma unroll
    for (int g = 0; g < 4; ++g) {
        const int ncol = g * E_ + w * 16 + col;
        #pragma unroll
        for (int s4 = 0; s4 < 4; ++s4) {
            const int k0 = s4 * 32 + kg * 8;
            half8 hb;
            #pragma unroll
            for (int e = 0; e < 8; ++e)
                hb[e] = (_Float16)Wh[(size_t)(k0 + e) * G4 + ncol];
            bf[g][s4] = hb;
        }
    }

    const int len = length[b];
    const float* zp = z_pre + (size_t)b * T_ * G4 + w * 16 + col;

    if (tid < E_) hbuf[0][tid] = (_Float16)0.f;
    float c_st = 0.f;                         // meaningful in kg==0 lanes

    // depth-2 pending sets (z_pre already contains b_lstm)
    const int t1 = (1 < len) ? 1 : 0;
    float zA0 = zp[0], zA1 = zp[E_], zA2 = zp[2 * E_], zA3 = zp[3 * E_];
    float zB0 = zp[(size_t)t1 * G4], zB1 = zp[(size_t)t1 * G4 + E_],
          zB2 = zp[(size_t)t1 * G4 + 2 * E_], zB3 = zp[(size_t)t1 * G4 + 3 * E_];
    __syncthreads();

#define LSTM_STEP(T, ZR0, ZR1, ZR2, ZR3, RBUF, WBUF)                          \
    {                                                                          \
        /* consume pending set (forces vmcnt wait for load issued at T-2) */   \
        float c0 = ZR0, c1 = ZR1, c2 = ZR2, c3 = ZR3;                          \
        /* re-issue this set for step T+2 (clamped; in flight ~2 steps) */     \
        {                                                                      \
            int tf = ((T) + 2 < len) ? (T) + 2 : len - 1;                      \
            const float* zf = zp + (size_t)tf * G4;                            \
            ZR0 = zf[0]; ZR1 = zf[E_]; ZR2 = zf[2 * E_]; ZR3 = zf[3 * E_];     \
        }                                                                      \
        half8 af0 = *(const half8*)&hbuf[RBUF][0 * 32 + kg * 8];               \
        half8 af1 = *(const half8*)&hbuf[RBUF][1 * 32 + kg * 8];               \
        half8 af2 = *(const half8*)&hbuf[RBUF][2 * 32 + kg * 8];               \
        half8 af3 = *(const half8*)&hbuf[RBUF][3 * 32 + kg * 8];               \
        floatx4 a0 = {c0, 0.f, 0.f, 0.f};                                      \
        floatx4 a1 = {c1, 0.f, 0.f, 0.f};                                      \
        floatx4 a2 = {c2, 0.f, 0.f, 0.f};                                      \
        floatx4 a3 = {c3, 0.f, 0.f, 0.f};                                      \
        a0 = __builtin_amdgcn_mfma_f32_16x16x32_f16(af0, bf[0][0], a0, 0, 0, 0); \
        a0 = __builtin_amdgcn_mfma_f32_16x16x32_f16(af1, bf[0][1], a0, 0, 0, 0); \
        a0 = __builtin_amdgcn_mfma_f32_16x16x32_f16(af2, bf[0][2], a0, 0, 0, 0); \
        a0 = __builtin_amdgcn_mfma_f32_16x16x32_f16(af3, bf[0][3], a0, 0, 0, 0); \
        a1 = __builtin_amdgcn_mfma_f32_16x16x32_f16(af0, bf[1][0], a1, 0, 0, 0); \
        a1 = __builtin_amdgcn_mfma_f32_16x16x32_f16(af1, bf[1][1], a1, 0, 0, 0); \
        a1 = __builtin_amdgcn_mfma_f32_16x16x32_f16(af2, bf[1][2], a1, 0, 0, 0); \
        a1 = __builtin_amdgcn_mfma_f32_16x16x32_f16(af3, bf[1][3], a1, 0, 0, 0); \
        a2 = __builtin_amdgcn_mfma_f32_16x16x32_f16(af0, bf[2][0], a2, 0, 0, 0); \
        a2 = __builtin_amdgcn_mfma_f32_16x16x32_f16(af1, bf[2][1], a2, 0, 0, 0); \
        a2 = __builtin_amdgcn_mfma_f32_16x16x32_f16(af2, bf[2][2], a2, 0, 0, 0); \
        a2 = __builtin_amdgcn_mfma_f32_16x16x32_f16(af3, bf[2][3], a2, 0, 0, 0); \
        a3 = __builtin_amdgcn_mfma_f32_16x16x32_f16(af0, bf[3][0], a3, 0, 0, 0); \
        a3 = __builtin_amdgcn_mfma_f32_16x16x32_f16(af1, bf[3][1], a3, 0, 0, 0); \
        a3 = __builtin_amdgcn_mfma_f32_16x16x32_f16(af2, bf[3][2], a3, 0, 0, 0); \
        a3 = __builtin_amdgcn_mfma_f32_16x16x32_f16(af3, bf[3][3], a3, 0, 0, 0); \
        float ig = sigmoid_fast(a0[0]);                                        \
        float fg = sigmoid_fast(a1[0]);                                        \
        float gg = tanh_fast(a2[0]);                                           \
        float og = sigmoid_fast(a3[0]);                                        \
        c_st = fg * c_st + ig * gg;                                            \
        float h = og * tanh_fast(c_st);                                        \
        if (kg == 0) {                                                         \
            hbuf[WBUF][w * 16 + col] = (_Float16)h;                            \
            if ((T) == len - 1) last_h[b * E_ + w * 16 + col] = h;             \
        }                                                                      \
        __syncthreads();                                                       \
    }

    for (int s = 0; s < len; s += 2) {
        LSTM_STEP(s, zA0, zA1, zA2, zA3, 0, 1)
        if (s + 1 >= len) break;
        LSTM_STEP(s + 1, zB0, zB1, zB2, zB3, 1, 0)
    }
#undef LSTM_STEP
}

// ---------------------------------------------------------------------------
// Kernel 4: MLP head + L2 normalize (unchanged).
// ---------------------------------------------------------------------------
__global__ __launch_bounds__(256) void mlp_kernel(
    const float* __restrict__ last_h, const float* __restrict__ W0,
    const float* __restrict__ b0, const float* __restrict__ W1,
    const float* __restrict__ b1, float* __restrict__ out)
{
    const int b = blockIdx.x;
    const int j = threadIdx.x;    // 0..255

    __shared__ float lrow[E_];
    __shared__ float hid[H_];
    __shared__ float red[H_];

    if (j < E_) lrow[j] = last_h[b * E_ + j];
    __syncthreads();

    float a = b0[j];
    #pragma unroll 8
    for (int k = 0; k < E_; ++k)
        a = fmaf(lrow[k], W0[k * H_ + j], a);
    hid[j] = fmaxf(a, 0.f);
    __syncthreads();

    float f = b1[j];
    #pragma unroll 8
    for (int k = 0; k < H_; ++k)
        f = fmaf(hid[k], W1[k * H_ + j], f);

    red[j] = f * f;
    __syncthreads();
    #pragma unroll
    for (int s = 128; s > 0; s >>= 1) {
        if (j < s) red[j] += red[j + s];
        __syncthreads();
    }
    out[(size_t)b * H_ + j] = f / sqrtf(red[0]);
}

// ---------------------------------------------------------------------------
extern "C" void kernel_launch(void* const* d_in, const int* in_sizes, int n_in,
                              void* d_out, int out_size, void* d_ws, size_t ws_size,
                              hipStream_t stream)
{
    const int*   code  = (const int*)  d_in[0];
    const float* aux   = (const float*)d_in[1];
    const int*   length= (const int*)  d_in[2];
    // d_in[3] = is_training (ignored; inference path)
    const float* W_lin = (const float*)d_in[4];
    const float* b_lin = (const float*)d_in[5];
    const float* W_x   = (const float*)d_in[6];
    const float* W_h   = (const float*)d_in[7];
    const float* b_lstm= (const float*)d_in[8];
    const float* W0    = (const float*)d_in[9];
    const float* b0    = (const float*)d_in[10];
    const float* W1    = (const float*)d_in[11];
    const float* b1    = (const float*)d_in[12];
    float* out = (float*)d_out;

    // workspace layout
    char* ws = (char*)d_ws;
    float* x      = (float*)ws;                                   // 25600*128 f32
    float* z_pre  = (float*)(ws + (size_t)B_ * T_ * E_ * 4);      // 25600*512 f32
    float* last_h = (float*)(ws + (size_t)B_ * T_ * E_ * 4
                                + (size_t)B_ * T_ * G4 * 4);      // 128*128 f32

    fe_kernel<<<B_ * T_, 128, 0, stream>>>(code, aux, W_lin, b_lin, length, x);
    gemm_kernel<<<dim3((B_ * T_) / 64, G4 / 64), 256, 0, stream>>>(x, W_x, b_lstm, length, z_pre);
    lstm_kernel<<<B_, 512, 0, stream>>>(z_pre, W_h, length, last_h);
    mlp_kernel<<<B_, H_, 0, stream>>>(last_h, W0, b0, W1, b1, out);
}